// Round 8
// baseline (2230.886 us; speedup 1.0000x reference)
//
#include <hip/hip_runtime.h>

#define TT 4000   // timesteps
#define HH 64     // hidden
#define NB 256    // batch
#define EE 128    // fc out

typedef __attribute__((ext_vector_type(2))) _Float16 h2;
typedef __attribute__((ext_vector_type(8))) _Float16 h8;
typedef __attribute__((ext_vector_type(4))) float f4;

__device__ __forceinline__ float ftanh(float x) {
    return fmaf(2.f, __builtin_amdgcn_rcpf(1.f + __expf(-2.f * x)), -1.f);
}

#if __has_builtin(__builtin_amdgcn_fdot2)
#define FDOT2(a, b, c) __builtin_amdgcn_fdot2((a), (b), (c), false)
#else
#define FDOT2(a, b, c) fmaf((float)(a).x, (float)(b).x, fmaf((float)(a).y, (float)(b).y, (c)))
#endif

#define H2V(V, i) (__builtin_shufflevector((V), (V), 2 * (i), 2 * (i) + 1))
#define MF(A, B, C) __builtin_amdgcn_mfma_f32_16x16x32_f16((A), (B), (C), 0, 0, 0)

// Wave-local gather: result = src from lane (addr/4). LDS pipe, no barrier.
__device__ __forceinline__ float bperm(int addr, float v) {
    return __int_as_float(__builtin_amdgcn_ds_bpermute(addr, __float_as_int(v)));
}

// 8 consecutive fp32 -> h8 (4 VGPRs).
__device__ __forceinline__ h8 ld8h(const float* p) {
    f4 a = ((const f4*)p)[0], c = ((const f4*)p)[1];
    return h8{(_Float16)a.x, (_Float16)a.y, (_Float16)a.z, (_Float16)a.w,
              (_Float16)c.x, (_Float16)c.y, (_Float16)c.z, (_Float16)c.w};
}

// R21: pipe-split hybrid. R20 measured the key constant: MfmaUtil 30.8% =>
// MFMA pipe busy 402cyc for 24 MFMA => ~16.7cyc/MFMA at 1 wave/SIMD. So
// all-MFMA dots (402) == all-fdot2 dots (~400 VALU, R17) — but they are
// DIFFERENT PIPES. Split: L1 on MFMA (16, ~270 pipe-cyc; R20's verified
// path, C-init .x-only — rows 4/8/12 also bias-inited so every lane's .x
// is a valid gate; .y/.z/.w accumulate bounded garbage, never read), L0 on
// fdot2 (lane (kgrp,c) owns one full row: gate=kgrp, n=w*16+c, k=64
// in-lane, no butterfly; 32 fdot2 issue under the in-flight MFMAs).
// Acts distributed: 2/lane (was 8 in R20): own L0 row + kgrp-selected L1
// acc; i/f/g/o regathered via ds_bpermute (wave-local, no barrier); cell
// redundant across kgrp (consistent); kgrp0 writes h0, kgrp1 writes h1.
//
// lane = 16*kgrp + c ; c = MFMA col = n offset ; kgrp = MFMA k-group AND
// gate index (0:i 1:f 2:g 3:o). A-frags: all 16 A-rows = h (replicated,
// R20-verified); C col=lane&15 (m89-verified).
//
// Layer pipelining (R3-R10): iter t computes L0 gates(t) from h0(t-1) and
// L1 gates(t-1) from {h0(t-1), h1(t-2)}; 1 barrier/step, h fp16 dbuf.
__global__ __launch_bounds__(256, 1)
void lstm2_fc_kernel(const float* __restrict__ x,      // [B, T, 1]
                     const float* __restrict__ W_ih0,  // [256, 1]
                     const float* __restrict__ W_hh0,  // [256, 64]
                     const float* __restrict__ b_ih0,  // [256]
                     const float* __restrict__ b_hh0,  // [256]
                     const float* __restrict__ W_ih1,  // [256, 64]
                     const float* __restrict__ W_hh1,  // [256, 64]
                     const float* __restrict__ b_ih1,  // [256]
                     const float* __restrict__ b_hh1,  // [256]
                     const float* __restrict__ W_fc,   // [128, 64]
                     const float* __restrict__ b_fc,   // [128]
                     float* __restrict__ out)          // [B, 128]
{
    const int b    = blockIdx.x;
    const int tid  = threadIdx.x;     // 0..255
    const int w    = tid >> 6;        // wave 0..3 -> n-range [w*16, w*16+16)
    const int lane = tid & 63;
    const int c    = lane & 15;       // MFMA col / n offset
    const int kgrp = lane >> 4;       // k-group AND gate index
    const int n    = w * 16 + c;

    __shared__ float x_s[TT];                          // 16 KB
    __shared__ __align__(16) _Float16 hbuf[2][2 * HH]; // [parity][h0|h1], fp16

    for (int t = tid; t < TT; t += 256) x_s[t] = x[(size_t)b * TT + t];
    if (tid < 4 * HH) ((_Float16*)hbuf)[tid] = (_Float16)0.f;

    // Rows: gate*64 + n (PyTorch i,f,g,o).
    const int rL = kgrp * HH + n;    // this lane's own L0 row (gate = kgrp)
    const int rI = 0 * HH + n, rF = 1 * HH + n, rG = 2 * HH + n, rO = 3 * HH + n;
    const int kb0 = kgrp * 8, kb1 = 32 + kgrp * 8;

    // --- L0 weights: own row, full k=64 -> 8 h8 (32 VGPRs) ---
    h8 Wl0 = ld8h(W_hh0 + rL * HH + 0),  Wl1 = ld8h(W_hh0 + rL * HH + 8);
    h8 Wl2 = ld8h(W_hh0 + rL * HH + 16), Wl3 = ld8h(W_hh0 + rL * HH + 24);
    h8 Wl4 = ld8h(W_hh0 + rL * HH + 32), Wl5 = ld8h(W_hh0 + rL * HH + 40);
    h8 Wl6 = ld8h(W_hh0 + rL * HH + 48), Wl7 = ld8h(W_hh0 + rL * HH + 56);

    // --- L1 B-fragments (R20-verified layout): 16 h8 (64 VGPRs) ---
    h8 BI1a = ld8h(W_ih1 + rI * HH + kb0), BI1b = ld8h(W_ih1 + rI * HH + kb1);
    h8 BF1a = ld8h(W_ih1 + rF * HH + kb0), BF1b = ld8h(W_ih1 + rF * HH + kb1);
    h8 BG1a = ld8h(W_ih1 + rG * HH + kb0), BG1b = ld8h(W_ih1 + rG * HH + kb1);
    h8 BO1a = ld8h(W_ih1 + rO * HH + kb0), BO1b = ld8h(W_ih1 + rO * HH + kb1);
    h8 BI1c = ld8h(W_hh1 + rI * HH + kb0), BI1d = ld8h(W_hh1 + rI * HH + kb1);
    h8 BF1c = ld8h(W_hh1 + rF * HH + kb0), BF1d = ld8h(W_hh1 + rF * HH + kb1);
    h8 BG1c = ld8h(W_hh1 + rG * HH + kb0), BG1d = ld8h(W_hh1 + rG * HH + kb1);
    h8 BO1c = ld8h(W_hh1 + rO * HH + kb0), BO1d = ld8h(W_hh1 + rO * HH + kb1);

    // Scalars: L0 bias/x-weight for OWN row; L1 biases per col (all 4 gates).
    float wx  = W_ih0[rL];
    float bb0 = b_ih0[rL] + b_hh0[rL];
    float bI1 = b_ih1[rI] + b_hh1[rI], bF1 = b_ih1[rF] + b_hh1[rF];
    float bG1 = b_ih1[rG] + b_hh1[rG], bO1 = b_ih1[rO] + b_hh1[rO];

    // Remat fences (R7/R9-proven).
    asm volatile("" : "+v"(Wl0), "+v"(Wl1), "+v"(Wl2), "+v"(Wl3),
                      "+v"(Wl4), "+v"(Wl5), "+v"(Wl6), "+v"(Wl7),
                      "+v"(BI1a), "+v"(BI1b), "+v"(BF1a), "+v"(BF1b));
    asm volatile("" : "+v"(BG1a), "+v"(BG1b), "+v"(BO1a), "+v"(BO1b),
                      "+v"(BI1c), "+v"(BI1d), "+v"(BF1c), "+v"(BF1d),
                      "+v"(BG1c), "+v"(BG1d), "+v"(BO1c), "+v"(BO1d));
    asm volatile("" : "+v"(wx), "+v"(bb0),
                      "+v"(bI1), "+v"(bF1), "+v"(bG1), "+v"(bO1));

    // act(z) = mm * rcp(1 + exp(kk*z)) + aa ; tanh only for gate g (kgrp==2).
    const bool isg = (kgrp == 2);
    const float kk = isg ? -2.f : -1.f;
    const float mm = isg ?  2.f :  1.f;
    const float aa = isg ? -1.f :  0.f;

    // bpermute byte-addrs for gathering i,f,g,o of this lane's col c.
    const int ai = 4 * (0 * 16 + c), af = 4 * (1 * 16 + c);
    const int ag = 4 * (2 * 16 + c), ao = 4 * (3 * 16 + c);

    float cc0 = 0.f, cc1 = 0.f;                 // redundant across kgrp
    f4 aI1 = {0.f, 0.f, 0.f, 0.f}, aF1 = {0.f, 0.f, 0.f, 0.f};
    f4 aG1 = {0.f, 0.f, 0.f, 0.f}, aO1 = {0.f, 0.f, 0.f, 0.f};

    __syncthreads();

    for (int t = 0; t <= TT; ++t) {
        const float xt = x_s[(t < TT) ? t : 0];
        const h8* hb = (const h8*)hbuf[t & 1];
        // A-frags (per-lane kgrp slice): h0 k-slices + h1 k-slices.
        h8 A0a = hb[kgrp],     A0b = hb[4 + kgrp];
        h8 A1a = hb[8 + kgrp], A1b = hb[12 + kgrp];
        // Full h0 (uniform-address broadcast reads) for the L0 fdot2 path.
        h8 H0 = hb[0], H1 = hb[1], H2 = hb[2], H3 = hb[3];
        h8 H4 = hb[4], H5 = hb[5], H6 = hb[6], H7 = hb[7];

        // --- L1 MFMA (issue first; grinds while VALU runs L0) ---
        aI1.x = bI1; aF1.x = bF1; aG1.x = bG1; aO1.x = bO1;
        aI1 = MF(A0a, BI1a, aI1); aF1 = MF(A0a, BF1a, aF1);
        aG1 = MF(A0a, BG1a, aG1); aO1 = MF(A0a, BO1a, aO1);
        aI1 = MF(A0b, BI1b, aI1); aF1 = MF(A0b, BF1b, aF1);
        aG1 = MF(A0b, BG1b, aG1); aO1 = MF(A0b, BO1b, aO1);
        aI1 = MF(A1a, BI1c, aI1); aF1 = MF(A1a, BF1c, aF1);
        aG1 = MF(A1a, BG1c, aG1); aO1 = MF(A1a, BO1c, aO1);
        aI1 = MF(A1b, BI1d, aI1); aF1 = MF(A1b, BF1d, aF1);
        aG1 = MF(A1b, BG1d, aG1); aO1 = MF(A1b, BO1d, aO1);

        // --- L0 fdot2: own row, full k=64 in-lane (no butterfly) ---
        float z0 = fmaf(xt, wx, bb0);
        z0 = FDOT2(H2V(Wl0,0), H2V(H0,0), z0); z0 = FDOT2(H2V(Wl0,1), H2V(H0,1), z0);
        z0 = FDOT2(H2V(Wl0,2), H2V(H0,2), z0); z0 = FDOT2(H2V(Wl0,3), H2V(H0,3), z0);
        z0 = FDOT2(H2V(Wl1,0), H2V(H1,0), z0); z0 = FDOT2(H2V(Wl1,1), H2V(H1,1), z0);
        z0 = FDOT2(H2V(Wl1,2), H2V(H1,2), z0); z0 = FDOT2(H2V(Wl1,3), H2V(H1,3), z0);
        z0 = FDOT2(H2V(Wl2,0), H2V(H2,0), z0); z0 = FDOT2(H2V(Wl2,1), H2V(H2,1), z0);
        z0 = FDOT2(H2V(Wl2,2), H2V(H2,2), z0); z0 = FDOT2(H2V(Wl2,3), H2V(H2,3), z0);
        z0 = FDOT2(H2V(Wl3,0), H2V(H3,0), z0); z0 = FDOT2(H2V(Wl3,1), H2V(H3,1), z0);
        z0 = FDOT2(H2V(Wl3,2), H2V(H3,2), z0); z0 = FDOT2(H2V(Wl3,3), H2V(H3,3), z0);
        z0 = FDOT2(H2V(Wl4,0), H2V(H4,0), z0); z0 = FDOT2(H2V(Wl4,1), H2V(H4,1), z0);
        z0 = FDOT2(H2V(Wl4,2), H2V(H4,2), z0); z0 = FDOT2(H2V(Wl4,3), H2V(H4,3), z0);
        z0 = FDOT2(H2V(Wl5,0), H2V(H5,0), z0); z0 = FDOT2(H2V(Wl5,1), H2V(H5,1), z0);
        z0 = FDOT2(H2V(Wl5,2), H2V(H5,2), z0); z0 = FDOT2(H2V(Wl5,3), H2V(H5,3), z0);
        z0 = FDOT2(H2V(Wl6,0), H2V(H6,0), z0); z0 = FDOT2(H2V(Wl6,1), H2V(H6,1), z0);
        z0 = FDOT2(H2V(Wl6,2), H2V(H6,2), z0); z0 = FDOT2(H2V(Wl6,3), H2V(H6,3), z0);
        z0 = FDOT2(H2V(Wl7,0), H2V(H7,0), z0); z0 = FDOT2(H2V(Wl7,1), H2V(H7,1), z0);
        z0 = FDOT2(H2V(Wl7,2), H2V(H7,2), z0); z0 = FDOT2(H2V(Wl7,3), H2V(H7,3), z0);

        // L0 act (1/lane) -> gather i,f,g,o -> redundant cell update.
        float e0  = __expf(kk * z0);
        float av0 = fmaf(mm, __builtin_amdgcn_rcpf(1.f + e0), aa);
        float i0 = bperm(ai, av0), f0 = bperm(af, av0);
        float g0 = bperm(ag, av0), o0 = bperm(ao, av0);
        float cn0 = fmaf(f0, cc0, i0 * g0);
        const bool ok0 = (t < TT), ok1 = (t > 0);
        cc0 = ok0 ? cn0 : cc0;
        float h0n = o0 * ftanh(cn0);

        // L1: select own-gate acc (.x valid in every lane), act, gather, cell.
        float z1 = (kgrp & 2) ? ((kgrp & 1) ? aO1.x : aG1.x)
                              : ((kgrp & 1) ? aF1.x : aI1.x);
        float e1  = __expf(kk * z1);
        float av1 = fmaf(mm, __builtin_amdgcn_rcpf(1.f + e1), aa);
        float i1 = bperm(ai, av1), f1 = bperm(af, av1);
        float g1 = bperm(ag, av1), o1 = bperm(ao, av1);
        float cn1 = fmaf(f1, cc1, i1 * g1);
        cc1 = ok1 ? cn1 : cc1;
        float h1n = o1 * ftanh(cn1);

        _Float16* hw = hbuf[(t + 1) & 1];
        if (kgrp == 0 && ok0) hw[n] = (_Float16)h0n;       // h0 writers
        if (kgrp == 1 && ok1) hw[HH + n] = (_Float16)h1n;  // h1 writers

        __syncthreads();                         // h exchange (double-buffered)
    }

    // FC on final h1 = h1(TT-1), in hbuf[(TT+1)&1][64..128).
    if (tid < EE) {
        const _Float16* h1f = &hbuf[(TT + 1) & 1][HH];
        float acc = b_fc[tid];
        const float4* wf = (const float4*)(W_fc + tid * HH);
        #pragma unroll
        for (int k = 0; k < HH / 4; ++k) {
            float4 v = wf[k];
            acc = fmaf(v.x, (float)h1f[4*k+0], acc);
            acc = fmaf(v.y, (float)h1f[4*k+1], acc);
            acc = fmaf(v.z, (float)h1f[4*k+2], acc);
            acc = fmaf(v.w, (float)h1f[4*k+3], acc);
        }
        out[(size_t)b * EE + tid] = acc;
    }
}

extern "C" void kernel_launch(void* const* d_in, const int* in_sizes, int n_in,
                              void* d_out, int out_size, void* d_ws, size_t ws_size,
                              hipStream_t stream) {
    const float* x     = (const float*)d_in[0];
    const float* W_ih0 = (const float*)d_in[1];
    const float* W_hh0 = (const float*)d_in[2];
    const float* b_ih0 = (const float*)d_in[3];
    const float* b_hh0 = (const float*)d_in[4];
    const float* W_ih1 = (const float*)d_in[5];
    const float* W_hh1 = (const float*)d_in[6];
    const float* b_ih1 = (const float*)d_in[7];
    const float* b_hh1 = (const float*)d_in[8];
    const float* W_fc  = (const float*)d_in[9];
    const float* b_fc  = (const float*)d_in[10];
    float* out = (float*)d_out;

    lstm2_fc_kernel<<<dim3(NB), dim3(256), 0, stream>>>(
        x, W_ih0, W_hh0, b_ih0, b_hh0, W_ih1, W_hh1, b_ih1, b_hh1, W_fc, b_fc, out);
}

// Round 9
// 1990.543 us; speedup vs baseline: 1.1207x; 1.1207x over previous
//
#include <hip/hip_runtime.h>

#define TT 4000   // timesteps
#define HH 64     // hidden
#define NB 256    // batch
#define EE 128    // fc out

typedef __attribute__((ext_vector_type(2))) _Float16 h2;
typedef __attribute__((ext_vector_type(8))) _Float16 h8;

#if __has_builtin(__builtin_amdgcn_fdot2)
#define FDOT2(a, b, c) __builtin_amdgcn_fdot2((a), (b), (c), false)
#else
#define FDOT2(a, b, c) fmaf((float)(a).x, (float)(b).x, fmaf((float)(a).y, (float)(b).y, (c)))
#endif

// h2 sub-extract from h8 register (sub-register addressing, no memory).
#define H2V(V, i) (__builtin_shufflevector((V), (V), 2 * (i), 2 * (i) + 1))

// DPP helpers (VALU pipe, no LDS). ctrl must be an ICE -> template param.
template <int CTRL>
__device__ __forceinline__ float dpp_mov(float v) {
    return __int_as_float(__builtin_amdgcn_update_dpp(
        0, __float_as_int(v), CTRL, 0xF, 0xF, true));
}
#define DPP_XOR1 0xB1   // quad_perm [1,0,3,2]  (flip s)      [HW-verified R8/R9]
#define DPP_XOR2 0x4E   // quad_perm [2,3,0,1]  (flip u)      [HW-verified R8/R9]
#define DPP_FB   0x44   // quad_perm [0,1,0,1]  (broadcast u=0 per s)
#define DPP_OB   0xEE   // quad_perm [2,3,2,3]  (broadcast u=1 per s)
#define DPP_SHR4 0x114  // row_shr:4            (p=0 quad -> p=1 quad) [R13-verified]

#define CVT2(d0, d1, s) h2 d0 = h2{(_Float16)(s).x, (_Float16)(s).y}, \
                           d1 = h2{(_Float16)(s).z, (_Float16)(s).w};

#define LOG2E 1.442695041f

// tanh via exp2 (constant pre-folded: exp(-2x) = exp2(-2*log2e*x)).
__device__ __forceinline__ float ftanh2(float x) {
    return fmaf(2.f, __builtin_amdgcn_rcpf(1.f + exp2f(-2.f * LOG2E * x)), -1.f);
}

// R22: serial-tail micro-cuts on R17 (1885us/1131cyc — the proven optimum of
// the 4-wave/1-per-SIMD/2n-per-lane family; R13-R21 falsified every
// structural alternative: wave count both ways, DPP read-rebuild, chain
// shape, MFMA/hybrid, multi-element). Step budget: DS+dots ~450, act tail
// ~170 (trans dep-latency serial), read lat ~120, write/drain/barrier ~150.
// Cuts: (1) exp2 constant-fold — __expf = mul(log2e)+v_exp; pre-fold the
// mul into kk -> one VALU op off EVERY act's serial chain; (2) adjacent-n
// pack: nb=na+1 (was +32) -> writer stores ONE h2 (b32) instead of two b16:
// DS writes 64->32/CU and shorter write->drain->barrier tail. n lives in
// lane bits >=3 so the DPP quad algebra is untouched; rows just re-index.
// (3) x_s[TT+1] pad kills the per-step (t<TT) select.
//
// lane = 16*rowgrp + 8*nn + 4*p + 2*u + s ; pair = w*8 + rowgrp*2 + nn ;
// na = 2*pair, nb = na+1 ; gate = p + 2u (p=0 quad: i,i,g,g ; p=1 quad:
// f,f,o,o), s = k-half AND layer assignment.
//
// Layer pipelining (verified R3-R10): iter t computes L0 gates(t) from
// h0(t-1) and L1 gates(t-1) from {h1(t-2), h0(t-1)}; s=0 lanes run the L0
// act/cell path, s=1 the L1 path. 1 barrier/step, h fp16 double-buffered.
__global__ __launch_bounds__(256, 1)
void lstm2_fc_kernel(const float* __restrict__ x,      // [B, T, 1]
                     const float* __restrict__ W_ih0,  // [256, 1]
                     const float* __restrict__ W_hh0,  // [256, 64]
                     const float* __restrict__ b_ih0,  // [256]
                     const float* __restrict__ b_hh0,  // [256]
                     const float* __restrict__ W_ih1,  // [256, 64]
                     const float* __restrict__ W_hh1,  // [256, 64]
                     const float* __restrict__ b_ih1,  // [256]
                     const float* __restrict__ b_hh1,  // [256]
                     const float* __restrict__ W_fc,   // [128, 64]
                     const float* __restrict__ b_fc,   // [128]
                     float* __restrict__ out)          // [B, 128]
{
    const int b    = blockIdx.x;
    const int tid  = threadIdx.x;     // 0..255
    const int w    = tid >> 6;        // wave 0..3
    const int lane = tid & 63;
    const int ss   = lane & 1;        // k-half AND layer assignment
    const int uu   = (lane >> 1) & 1;
    const int pp   = (lane >> 2) & 1;
    const int nn   = (lane >> 3) & 1;
    const int pair = w * 8 + (lane >> 4) * 2 + nn;   // 0..31
    const int na   = 2 * pair;                        // even h-index
    const int nb   = na + 1;                          // odd  h-index
    const int gidx = pp + 2 * uu;                    // 0:i 1:f 2:g 3:o

    __shared__ float x_s[TT + 1];                      // 16 KB (+pad)
    __shared__ __align__(16) _Float16 hbuf[2][2 * HH]; // [parity][h0|h1], fp16

    for (int t = tid; t < TT; t += 256) x_s[t] = x[(size_t)b * TT + t];
    if (tid == 0) x_s[TT] = 0.f;
    if (tid < 4 * HH) ((_Float16*)hbuf)[tid] = (_Float16)0.f;

    const int rowa = gidx * HH + na;   // gate row in [0,256)
    const int rowb = rowa + 1;
    // --- Named-scalar weight load: 6 thirty-two-wide slices -> 96 h2 ---
    const float4* p0 = (const float4*)(W_hh0 + rowa * HH + ss * 32);
    const float4* p1 = (const float4*)(W_ih1 + rowa * HH + ss * 32);
    const float4* p2 = (const float4*)(W_hh1 + rowa * HH + ss * 32);
    const float4* p3 = (const float4*)(W_hh0 + rowb * HH + ss * 32);
    const float4* p4 = (const float4*)(W_ih1 + rowb * HH + ss * 32);
    const float4* p5 = (const float4*)(W_hh1 + rowb * HH + ss * 32);
    float4 qa0 = p0[0], qa1 = p0[1], qa2 = p0[2], qa3 = p0[3];
    float4 qa4 = p0[4], qa5 = p0[5], qa6 = p0[6], qa7 = p0[7];
    float4 qb0 = p1[0], qb1 = p1[1], qb2 = p1[2], qb3 = p1[3];
    float4 qb4 = p1[4], qb5 = p1[5], qb6 = p1[6], qb7 = p1[7];
    float4 qc0 = p2[0], qc1 = p2[1], qc2 = p2[2], qc3 = p2[3];
    float4 qc4 = p2[4], qc5 = p2[5], qc6 = p2[6], qc7 = p2[7];
    float4 qd0 = p3[0], qd1 = p3[1], qd2 = p3[2], qd3 = p3[3];
    float4 qd4 = p3[4], qd5 = p3[5], qd6 = p3[6], qd7 = p3[7];
    float4 qe0 = p4[0], qe1 = p4[1], qe2 = p4[2], qe3 = p4[3];
    float4 qe4 = p4[4], qe5 = p4[5], qe6 = p4[6], qe7 = p4[7];
    float4 qf0 = p5[0], qf1 = p5[1], qf2 = p5[2], qf3 = p5[3];
    float4 qf4 = p5[4], qf5 = p5[5], qf6 = p5[6], qf7 = p5[7];
    CVT2(A0,  A1,  qa0) CVT2(A2,  A3,  qa1) CVT2(A4,  A5,  qa2) CVT2(A6,  A7,  qa3)
    CVT2(A8,  A9,  qa4) CVT2(A10, A11, qa5) CVT2(A12, A13, qa6) CVT2(A14, A15, qa7)
    CVT2(B0,  B1,  qb0) CVT2(B2,  B3,  qb1) CVT2(B4,  B5,  qb2) CVT2(B6,  B7,  qb3)
    CVT2(B8,  B9,  qb4) CVT2(B10, B11, qb5) CVT2(B12, B13, qb6) CVT2(B14, B15, qb7)
    CVT2(C0,  C1,  qc0) CVT2(C2,  C3,  qc1) CVT2(C4,  C5,  qc2) CVT2(C6,  C7,  qc3)
    CVT2(C8,  C9,  qc4) CVT2(C10, C11, qc5) CVT2(C12, C13, qc6) CVT2(C14, C15, qc7)
    CVT2(D0,  D1,  qd0) CVT2(D2,  D3,  qd1) CVT2(D4,  D5,  qd2) CVT2(D6,  D7,  qd3)
    CVT2(D8,  D9,  qd4) CVT2(D10, D11, qd5) CVT2(D12, D13, qd6) CVT2(D14, D15, qd7)
    CVT2(E0,  E1,  qe0) CVT2(E2,  E3,  qe1) CVT2(E4,  E5,  qe2) CVT2(E6,  E7,  qe3)
    CVT2(E8,  E9,  qe4) CVT2(E10, E11, qe5) CVT2(E12, E13, qe6) CVT2(E14, E15, qe7)
    CVT2(F0,  F1,  qf0) CVT2(F2,  F3,  qf1) CVT2(F4,  F5,  qf2) CVT2(F6,  F7,  qf3)
    CVT2(F8,  F9,  qf4) CVT2(F10, F11, qf5) CVT2(F12, F13, qf6) CVT2(F14, F15, qf7)

    float wxa  = W_ih0[rowa];
    float wxb  = W_ih0[rowb];
    float bb0a = b_ih0[rowa] + b_hh0[rowa];
    float bb0b = b_ih0[rowb] + b_hh0[rowb];
    float bb1a = b_ih1[rowa] + b_hh1[rowa];
    float bb1b = b_ih1[rowb] + b_hh1[rowb];

    // Remat fences (R7/R9-proven). <=24 operands each (inline-asm limit margin).
    asm volatile("" : "+v"(A0), "+v"(A1), "+v"(A2),  "+v"(A3),
                      "+v"(A4), "+v"(A5), "+v"(A6),  "+v"(A7),
                      "+v"(A8), "+v"(A9), "+v"(A10), "+v"(A11),
                      "+v"(A12),"+v"(A13),"+v"(A14), "+v"(A15),
                      "+v"(B0), "+v"(B1), "+v"(B2),  "+v"(B3),
                      "+v"(B4), "+v"(B5), "+v"(B6),  "+v"(B7));
    asm volatile("" : "+v"(B8), "+v"(B9), "+v"(B10), "+v"(B11),
                      "+v"(B12),"+v"(B13),"+v"(B14), "+v"(B15),
                      "+v"(C0), "+v"(C1), "+v"(C2),  "+v"(C3),
                      "+v"(C4), "+v"(C5), "+v"(C6),  "+v"(C7),
                      "+v"(C8), "+v"(C9), "+v"(C10), "+v"(C11),
                      "+v"(C12),"+v"(C13),"+v"(C14), "+v"(C15));
    asm volatile("" : "+v"(D0), "+v"(D1), "+v"(D2),  "+v"(D3),
                      "+v"(D4), "+v"(D5), "+v"(D6),  "+v"(D7),
                      "+v"(D8), "+v"(D9), "+v"(D10), "+v"(D11),
                      "+v"(D12),"+v"(D13),"+v"(D14), "+v"(D15),
                      "+v"(E0), "+v"(E1), "+v"(E2),  "+v"(E3),
                      "+v"(E4), "+v"(E5), "+v"(E6),  "+v"(E7));
    asm volatile("" : "+v"(E8), "+v"(E9), "+v"(E10), "+v"(E11),
                      "+v"(E12),"+v"(E13),"+v"(E14), "+v"(E15),
                      "+v"(F0), "+v"(F1), "+v"(F2),  "+v"(F3),
                      "+v"(F4), "+v"(F5), "+v"(F6),  "+v"(F7),
                      "+v"(F8), "+v"(F9), "+v"(F10), "+v"(F11),
                      "+v"(F12),"+v"(F13),"+v"(F14), "+v"(F15));
    asm volatile("" : "+v"(wxa), "+v"(wxb), "+v"(bb0a),
                      "+v"(bb0b),"+v"(bb1a),"+v"(bb1b));

    // act(z) = mm * rcp(1 + exp2(kk2*z)) + aa ; tanh only for g (gidx==2).
    // kk2 pre-folds log2e (saves one mul on every act's serial chain).
    const bool isg = (gidx == 2);
    const float kk2 = isg ? -2.f * LOG2E : -LOG2E;
    const float mm = isg ?  2.f :  1.f;
    const float aa = isg ? -1.f :  0.f;

    const bool wlane = (pp == 1) && (uu == 0);   // h writers (f lanes)
    const int  hoff  = ss * HH + na;             // even -> h2-aligned pack
    float cca = 0.f, ccb = 0.f;                  // valid in p=1 lanes

    __syncthreads();

    // One fdot2 from each of the 6 chains; same-acc dependents spaced 6
    // instrs (12 issue-cyc) -> no latency stall on in-order issue.
    #define ROW(Aj, Dj, Bj, Ej, Cj, Fj, Hv, Gv, e) \
        s0a = FDOT2(Aj, H2V(Hv, e), s0a); \
        s0b = FDOT2(Dj, H2V(Hv, e), s0b); \
        s1a = FDOT2(Bj, H2V(Hv, e), s1a); \
        s1b = FDOT2(Ej, H2V(Hv, e), s1b); \
        s2a = FDOT2(Cj, H2V(Gv, e), s2a); \
        s2b = FDOT2(Fj, H2V(Gv, e), s2b);

    for (int t = 0; t <= TT; ++t) {
        const float xt = x_s[t];
        const h8* hb = (const h8*)hbuf[t & 1];
        // 8 b128 broadcast reads, ordered to match consumption (H,G pairs).
        h8 Ha = hb[4 * ss + 0], Ga = hb[8 + 4 * ss + 0];
        h8 Hc = hb[4 * ss + 1], Gc = hb[8 + 4 * ss + 1];
        h8 He = hb[4 * ss + 2], Ge = hb[8 + 4 * ss + 2];
        h8 Hg = hb[4 * ss + 3], Gg = hb[8 + 4 * ss + 3];

        // 6 chains, 16 links each.
        float s0a = ss ? 0.f : fmaf(xt, wxa, bb0a);   // A: L0(a)
        float s0b = ss ? 0.f : fmaf(xt, wxb, bb0b);   // D: L0(b)
        float s1a = ss ? 0.f : bb1a;                  // B: L1(a) h0-part
        float s1b = ss ? 0.f : bb1b;                  // E: L1(b) h0-part
        float s2a = 0.f;                              // C: L1(a) h1-part
        float s2b = 0.f;                              // F: L1(b) h1-part

        ROW(A0,  D0,  B0,  E0,  C0,  F0,  Ha, Ga, 0)
        ROW(A1,  D1,  B1,  E1,  C1,  F1,  Ha, Ga, 1)
        ROW(A2,  D2,  B2,  E2,  C2,  F2,  Ha, Ga, 2)
        ROW(A3,  D3,  B3,  E3,  C3,  F3,  Ha, Ga, 3)
        ROW(A4,  D4,  B4,  E4,  C4,  F4,  Hc, Gc, 0)
        ROW(A5,  D5,  B5,  E5,  C5,  F5,  Hc, Gc, 1)
        ROW(A6,  D6,  B6,  E6,  C6,  F6,  Hc, Gc, 2)
        ROW(A7,  D7,  B7,  E7,  C7,  F7,  Hc, Gc, 3)
        ROW(A8,  D8,  B8,  E8,  C8,  F8,  He, Ge, 0)
        ROW(A9,  D9,  B9,  E9,  C9,  F9,  He, Ge, 1)
        ROW(A10, D10, B10, E10, C10, F10, He, Ge, 2)
        ROW(A11, D11, B11, E11, C11, F11, He, Ge, 3)
        ROW(A12, D12, B12, E12, C12, F12, Hg, Gg, 0)
        ROW(A13, D13, B13, E13, C13, F13, Hg, Gg, 1)
        ROW(A14, D14, B14, E14, C14, F14, Hg, Gg, 2)
        ROW(A15, D15, B15, E15, C15, F15, Hg, Gg, 3)

        float acc0a = s0a;
        float acc0b = s0b;
        float acc1a = s1a + s2a;
        float acc1b = s1b + s2b;

        // s-butterfly (DPP xor1): both s-lanes hold full row sums.
        acc0a += dpp_mov<DPP_XOR1>(acc0a);
        acc0b += dpp_mov<DPP_XOR1>(acc0b);
        acc1a += dpp_mov<DPP_XOR1>(acc1a);
        acc1b += dpp_mov<DPP_XOR1>(acc1b);

        // Per-lane layer: s=0 -> L0(t), s=1 -> L1(t-1). One activation per n.
        float za  = ss ? acc1a : acc0a;
        float zb  = ss ? acc1b : acc0b;
        float eza = exp2f(kk2 * za);
        float ezb = exp2f(kk2 * zb);
        float va  = fmaf(mm, __builtin_amdgcn_rcpf(1.f + eza), aa);
        float vb  = fmaf(mm, __builtin_amdgcn_rcpf(1.f + ezb), aa);

        // Gate combine, all DPP (independent per n-path):
        //  p=0 quad (i,i,g,g): ig = val * xor2(val)     [per s]
        //  row_shr:4 hands ig to the p=1 quad (f,f,o,o) [dest i <- src i-4]
        //  f/o broadcast per s via quad_perm 0x44/0xEE
        float igqa = va * dpp_mov<DPP_XOR2>(va);
        float igqb = vb * dpp_mov<DPP_XOR2>(vb);
        float iga  = dpp_mov<DPP_SHR4>(igqa);
        float igb  = dpp_mov<DPP_SHR4>(igqb);
        float fba  = dpp_mov<DPP_FB>(va);
        float fbb  = dpp_mov<DPP_FB>(vb);
        float oba  = dpp_mov<DPP_OB>(va);
        float obb  = dpp_mov<DPP_OB>(vb);

        float cna = fmaf(fba, cca, iga);
        float cnb = fmaf(fbb, ccb, igb);
        float hna = oba * ftanh2(cna);
        float hnb = obb * ftanh2(cnb);
        bool ok = ss ? (t > 0) : (t < TT);       // L1 skip at 0, L0 at TT
        cca = ok ? cna : cca;
        ccb = ok ? cnb : ccb;
        if (wlane && ok) {
            // Adjacent na,nb -> single packed h2 (b32) store.
            *(h2*)&hbuf[(t + 1) & 1][hoff] = h2{(_Float16)hna, (_Float16)hnb};
        }

        __syncthreads();                         // h exchange (double-buffered)
    }
    #undef ROW

    // FC on final h1 = h1(TT-1), in hbuf[(TT+1)&1][64..128).
    if (tid < EE) {
        const _Float16* h1f = &hbuf[(TT + 1) & 1][HH];
        float acc = b_fc[tid];
        const float4* wf = (const float4*)(W_fc + tid * HH);
        #pragma unroll
        for (int k = 0; k < HH / 4; ++k) {
            float4 v = wf[k];
            acc = fmaf(v.x, (float)h1f[4*k+0], acc);
            acc = fmaf(v.y, (float)h1f[4*k+1], acc);
            acc = fmaf(v.z, (float)h1f[4*k+2], acc);
            acc = fmaf(v.w, (float)h1f[4*k+3], acc);
        }
        out[(size_t)b * EE + tid] = acc;
    }
}

extern "C" void kernel_launch(void* const* d_in, const int* in_sizes, int n_in,
                              void* d_out, int out_size, void* d_ws, size_t ws_size,
                              hipStream_t stream) {
    const float* x     = (const float*)d_in[0];
    const float* W_ih0 = (const float*)d_in[1];
    const float* W_hh0 = (const float*)d_in[2];
    const float* b_ih0 = (const float*)d_in[3];
    const float* b_hh0 = (const float*)d_in[4];
    const float* W_ih1 = (const float*)d_in[5];
    const float* W_hh1 = (const float*)d_in[6];
    const float* b_ih1 = (const float*)d_in[7];
    const float* b_hh1 = (const float*)d_in[8];
    const float* W_fc  = (const float*)d_in[9];
    const float* b_fc  = (const float*)d_in[10];
    float* out = (float*)d_out;

    lstm2_fc_kernel<<<dim3(NB), dim3(256), 0, stream>>>(
        x, W_ih0, W_hh0, b_ih0, b_hh0, W_ih1, W_hh1, b_ih1, b_hh1, W_fc, b_fc, out);
}

// Round 10
// 1821.311 us; speedup vs baseline: 1.2249x; 1.0929x over previous
//
#include <hip/hip_runtime.h>

#define TT 4000   // timesteps
#define HH 64     // hidden
#define NB 256    // batch
#define EE 128    // fc out

typedef __attribute__((ext_vector_type(2))) _Float16 h2;
typedef __attribute__((ext_vector_type(8))) _Float16 h8;

#if __has_builtin(__builtin_amdgcn_fdot2)
#define FDOT2(a, b, c) __builtin_amdgcn_fdot2((a), (b), (c), false)
#else
#define FDOT2(a, b, c) fmaf((float)(a).x, (float)(b).x, fmaf((float)(a).y, (float)(b).y, (c)))
#endif

// h2 sub-extract from h8 register (sub-register addressing, no memory).
#define H2V(V, i) (__builtin_shufflevector((V), (V), 2 * (i), 2 * (i) + 1))

// DPP helpers (VALU pipe, no LDS). ctrl must be an ICE -> template param.
template <int CTRL>
__device__ __forceinline__ float dpp_mov(float v) {
    return __int_as_float(__builtin_amdgcn_update_dpp(
        0, __float_as_int(v), CTRL, 0xF, 0xF, true));
}
#define DPP_XOR1 0xB1   // quad_perm [1,0,3,2]  (flip s)      [HW-verified R8/R9]
#define DPP_XOR2 0x4E   // quad_perm [2,3,0,1]  (flip u)      [HW-verified R8/R9]
#define DPP_FB   0x44   // quad_perm [0,1,0,1]  (broadcast u=0 per s)
#define DPP_OB   0xEE   // quad_perm [2,3,2,3]  (broadcast u=1 per s)
#define DPP_SHR4 0x114  // row_shr:4            (p=0 quad -> p=1 quad) [R13-verified]

#define CVT2(d0, d1, s) h2 d0 = h2{(_Float16)(s).x, (_Float16)(s).y}, \
                           d1 = h2{(_Float16)(s).z, (_Float16)(s).w};

#define LOG2E 1.442695041f

// Raw HW 2^x (v_exp_f32) — R22's libm exp2f carried denorm/range fixups on
// every act's serial chain (+116cyc/step); this is the fast path.
#if __has_builtin(__builtin_amdgcn_exp2f)
__device__ __forceinline__ float fexp2(float x) { return __builtin_amdgcn_exp2f(x); }
#else
__device__ __forceinline__ float fexp2(float x) { return __expf(x * 0.6931471805599453f); }
#endif

// tanh via raw exp2 (constant pre-folded).
__device__ __forceinline__ float ftanh2(float x) {
    return fmaf(2.f, __builtin_amdgcn_rcpf(1.f + fexp2(-2.f * LOG2E * x)), -1.f);
}

// R23: A/B fix of R22. R22's diagnostic: SQ_LDS_BANK_CONFLICT exactly halved
// (1.638e7 -> 8.19e6; packed b32 h-write verified effective) yet time rose
// +116cyc/step -> the regression is exp2f = libm __ocml_exp2_f32 (denorm
// fixup branches) on every act's serial chain, NOT the write change. Fix:
// __builtin_amdgcn_exp2f (raw v_exp_f32). With pre-folded kk2 = kk*log2e
// each act = 1 mul + 1 v_exp (vs __expf's 2 muls + v_exp). Keeps R22's
// packed adjacent-n write (nb=na+1, one h2 b32 store, DS writes 64->32/CU)
// and x_s[TT+1] pad. Base structure = R17 (4 waves, 1/SIMD, 2n/lane,
// 6-chain round-robin dots, DPP gate algebra) — proven optimum of the
// family (R13-R21 falsified all structural alternatives).
//
// lane = 16*rowgrp + 8*nn + 4*p + 2*u + s ; pair = w*8 + rowgrp*2 + nn ;
// na = 2*pair, nb = na+1 ; gate = p + 2u (p=0 quad: i,i,g,g ; p=1 quad:
// f,f,o,o), s = k-half AND layer assignment.
//
// Layer pipelining (verified R3-R10): iter t computes L0 gates(t) from
// h0(t-1) and L1 gates(t-1) from {h1(t-2), h0(t-1)}; s=0 lanes run the L0
// act/cell path, s=1 the L1 path. 1 barrier/step, h fp16 double-buffered.
__global__ __launch_bounds__(256, 1)
void lstm2_fc_kernel(const float* __restrict__ x,      // [B, T, 1]
                     const float* __restrict__ W_ih0,  // [256, 1]
                     const float* __restrict__ W_hh0,  // [256, 64]
                     const float* __restrict__ b_ih0,  // [256]
                     const float* __restrict__ b_hh0,  // [256]
                     const float* __restrict__ W_ih1,  // [256, 64]
                     const float* __restrict__ W_hh1,  // [256, 64]
                     const float* __restrict__ b_ih1,  // [256]
                     const float* __restrict__ b_hh1,  // [256]
                     const float* __restrict__ W_fc,   // [128, 64]
                     const float* __restrict__ b_fc,   // [128]
                     float* __restrict__ out)          // [B, 128]
{
    const int b    = blockIdx.x;
    const int tid  = threadIdx.x;     // 0..255
    const int w    = tid >> 6;        // wave 0..3
    const int lane = tid & 63;
    const int ss   = lane & 1;        // k-half AND layer assignment
    const int uu   = (lane >> 1) & 1;
    const int pp   = (lane >> 2) & 1;
    const int nn   = (lane >> 3) & 1;
    const int pair = w * 8 + (lane >> 4) * 2 + nn;   // 0..31
    const int na   = 2 * pair;                        // even h-index
    const int nb   = na + 1;                          // odd  h-index
    const int gidx = pp + 2 * uu;                    // 0:i 1:f 2:g 3:o

    __shared__ float x_s[TT + 1];                      // 16 KB (+pad)
    __shared__ __align__(16) _Float16 hbuf[2][2 * HH]; // [parity][h0|h1], fp16

    for (int t = tid; t < TT; t += 256) x_s[t] = x[(size_t)b * TT + t];
    if (tid == 0) x_s[TT] = 0.f;
    if (tid < 4 * HH) ((_Float16*)hbuf)[tid] = (_Float16)0.f;

    const int rowa = gidx * HH + na;   // gate row in [0,256)
    const int rowb = rowa + 1;
    // --- Named-scalar weight load: 6 thirty-two-wide slices -> 96 h2 ---
    const float4* p0 = (const float4*)(W_hh0 + rowa * HH + ss * 32);
    const float4* p1 = (const float4*)(W_ih1 + rowa * HH + ss * 32);
    const float4* p2 = (const float4*)(W_hh1 + rowa * HH + ss * 32);
    const float4* p3 = (const float4*)(W_hh0 + rowb * HH + ss * 32);
    const float4* p4 = (const float4*)(W_ih1 + rowb * HH + ss * 32);
    const float4* p5 = (const float4*)(W_hh1 + rowb * HH + ss * 32);
    float4 qa0 = p0[0], qa1 = p0[1], qa2 = p0[2], qa3 = p0[3];
    float4 qa4 = p0[4], qa5 = p0[5], qa6 = p0[6], qa7 = p0[7];
    float4 qb0 = p1[0], qb1 = p1[1], qb2 = p1[2], qb3 = p1[3];
    float4 qb4 = p1[4], qb5 = p1[5], qb6 = p1[6], qb7 = p1[7];
    float4 qc0 = p2[0], qc1 = p2[1], qc2 = p2[2], qc3 = p2[3];
    float4 qc4 = p2[4], qc5 = p2[5], qc6 = p2[6], qc7 = p2[7];
    float4 qd0 = p3[0], qd1 = p3[1], qd2 = p3[2], qd3 = p3[3];
    float4 qd4 = p3[4], qd5 = p3[5], qd6 = p3[6], qd7 = p3[7];
    float4 qe0 = p4[0], qe1 = p4[1], qe2 = p4[2], qe3 = p4[3];
    float4 qe4 = p4[4], qe5 = p4[5], qe6 = p4[6], qe7 = p4[7];
    float4 qf0 = p5[0], qf1 = p5[1], qf2 = p5[2], qf3 = p5[3];
    float4 qf4 = p5[4], qf5 = p5[5], qf6 = p5[6], qf7 = p5[7];
    CVT2(A0,  A1,  qa0) CVT2(A2,  A3,  qa1) CVT2(A4,  A5,  qa2) CVT2(A6,  A7,  qa3)
    CVT2(A8,  A9,  qa4) CVT2(A10, A11, qa5) CVT2(A12, A13, qa6) CVT2(A14, A15, qa7)
    CVT2(B0,  B1,  qb0) CVT2(B2,  B3,  qb1) CVT2(B4,  B5,  qb2) CVT2(B6,  B7,  qb3)
    CVT2(B8,  B9,  qb4) CVT2(B10, B11, qb5) CVT2(B12, B13, qb6) CVT2(B14, B15, qb7)
    CVT2(C0,  C1,  qc0) CVT2(C2,  C3,  qc1) CVT2(C4,  C5,  qc2) CVT2(C6,  C7,  qc3)
    CVT2(C8,  C9,  qc4) CVT2(C10, C11, qc5) CVT2(C12, C13, qc6) CVT2(C14, C15, qc7)
    CVT2(D0,  D1,  qd0) CVT2(D2,  D3,  qd1) CVT2(D4,  D5,  qd2) CVT2(D6,  D7,  qd3)
    CVT2(D8,  D9,  qd4) CVT2(D10, D11, qd5) CVT2(D12, D13, qd6) CVT2(D14, D15, qd7)
    CVT2(E0,  E1,  qe0) CVT2(E2,  E3,  qe1) CVT2(E4,  E5,  qe2) CVT2(E6,  E7,  qe3)
    CVT2(E8,  E9,  qe4) CVT2(E10, E11, qe5) CVT2(E12, E13, qe6) CVT2(E14, E15, qe7)
    CVT2(F0,  F1,  qf0) CVT2(F2,  F3,  qf1) CVT2(F4,  F5,  qf2) CVT2(F6,  F7,  qf3)
    CVT2(F8,  F9,  qf4) CVT2(F10, F11, qf5) CVT2(F12, F13, qf6) CVT2(F14, F15, qf7)

    float wxa  = W_ih0[rowa];
    float wxb  = W_ih0[rowb];
    float bb0a = b_ih0[rowa] + b_hh0[rowa];
    float bb0b = b_ih0[rowb] + b_hh0[rowb];
    float bb1a = b_ih1[rowa] + b_hh1[rowa];
    float bb1b = b_ih1[rowb] + b_hh1[rowb];

    // Remat fences (R7/R9-proven). <=24 operands each (inline-asm limit margin).
    asm volatile("" : "+v"(A0), "+v"(A1), "+v"(A2),  "+v"(A3),
                      "+v"(A4), "+v"(A5), "+v"(A6),  "+v"(A7),
                      "+v"(A8), "+v"(A9), "+v"(A10), "+v"(A11),
                      "+v"(A12),"+v"(A13),"+v"(A14), "+v"(A15),
                      "+v"(B0), "+v"(B1), "+v"(B2),  "+v"(B3),
                      "+v"(B4), "+v"(B5), "+v"(B6),  "+v"(B7));
    asm volatile("" : "+v"(B8), "+v"(B9), "+v"(B10), "+v"(B11),
                      "+v"(B12),"+v"(B13),"+v"(B14), "+v"(B15),
                      "+v"(C0), "+v"(C1), "+v"(C2),  "+v"(C3),
                      "+v"(C4), "+v"(C5), "+v"(C6),  "+v"(C7),
                      "+v"(C8), "+v"(C9), "+v"(C10), "+v"(C11),
                      "+v"(C12),"+v"(C13),"+v"(C14), "+v"(C15));
    asm volatile("" : "+v"(D0), "+v"(D1), "+v"(D2),  "+v"(D3),
                      "+v"(D4), "+v"(D5), "+v"(D6),  "+v"(D7),
                      "+v"(D8), "+v"(D9), "+v"(D10), "+v"(D11),
                      "+v"(D12),"+v"(D13),"+v"(D14), "+v"(D15),
                      "+v"(E0), "+v"(E1), "+v"(E2),  "+v"(E3),
                      "+v"(E4), "+v"(E5), "+v"(E6),  "+v"(E7));
    asm volatile("" : "+v"(E8), "+v"(E9), "+v"(E10), "+v"(E11),
                      "+v"(E12),"+v"(E13),"+v"(E14), "+v"(E15),
                      "+v"(F0), "+v"(F1), "+v"(F2),  "+v"(F3),
                      "+v"(F4), "+v"(F5), "+v"(F6),  "+v"(F7),
                      "+v"(F8), "+v"(F9), "+v"(F10), "+v"(F11),
                      "+v"(F12),"+v"(F13),"+v"(F14), "+v"(F15));
    asm volatile("" : "+v"(wxa), "+v"(wxb), "+v"(bb0a),
                      "+v"(bb0b),"+v"(bb1a),"+v"(bb1b));

    // act(z) = mm * rcp(1 + exp2(kk2*z)) + aa ; tanh only for g (gidx==2).
    // kk2 pre-folds log2e: 1 mul + 1 raw v_exp per act.
    const bool isg = (gidx == 2);
    const float kk2 = isg ? -2.f * LOG2E : -LOG2E;
    const float mm = isg ?  2.f :  1.f;
    const float aa = isg ? -1.f :  0.f;

    const bool wlane = (pp == 1) && (uu == 0);   // h writers (f lanes)
    const int  hoff  = ss * HH + na;             // even -> h2-aligned pack
    float cca = 0.f, ccb = 0.f;                  // valid in p=1 lanes

    __syncthreads();

    // One fdot2 from each of the 6 chains; same-acc dependents spaced 6
    // instrs (12 issue-cyc) -> no latency stall on in-order issue.
    #define ROW(Aj, Dj, Bj, Ej, Cj, Fj, Hv, Gv, e) \
        s0a = FDOT2(Aj, H2V(Hv, e), s0a); \
        s0b = FDOT2(Dj, H2V(Hv, e), s0b); \
        s1a = FDOT2(Bj, H2V(Hv, e), s1a); \
        s1b = FDOT2(Ej, H2V(Hv, e), s1b); \
        s2a = FDOT2(Cj, H2V(Gv, e), s2a); \
        s2b = FDOT2(Fj, H2V(Gv, e), s2b);

    for (int t = 0; t <= TT; ++t) {
        const float xt = x_s[t];
        const h8* hb = (const h8*)hbuf[t & 1];
        // 8 b128 broadcast reads, ordered to match consumption (H,G pairs).
        h8 Ha = hb[4 * ss + 0], Ga = hb[8 + 4 * ss + 0];
        h8 Hc = hb[4 * ss + 1], Gc = hb[8 + 4 * ss + 1];
        h8 He = hb[4 * ss + 2], Ge = hb[8 + 4 * ss + 2];
        h8 Hg = hb[4 * ss + 3], Gg = hb[8 + 4 * ss + 3];

        // 6 chains, 16 links each.
        float s0a = ss ? 0.f : fmaf(xt, wxa, bb0a);   // A: L0(a)
        float s0b = ss ? 0.f : fmaf(xt, wxb, bb0b);   // D: L0(b)
        float s1a = ss ? 0.f : bb1a;                  // B: L1(a) h0-part
        float s1b = ss ? 0.f : bb1b;                  // E: L1(b) h0-part
        float s2a = 0.f;                              // C: L1(a) h1-part
        float s2b = 0.f;                              // F: L1(b) h1-part

        ROW(A0,  D0,  B0,  E0,  C0,  F0,  Ha, Ga, 0)
        ROW(A1,  D1,  B1,  E1,  C1,  F1,  Ha, Ga, 1)
        ROW(A2,  D2,  B2,  E2,  C2,  F2,  Ha, Ga, 2)
        ROW(A3,  D3,  B3,  E3,  C3,  F3,  Ha, Ga, 3)
        ROW(A4,  D4,  B4,  E4,  C4,  F4,  Hc, Gc, 0)
        ROW(A5,  D5,  B5,  E5,  C5,  F5,  Hc, Gc, 1)
        ROW(A6,  D6,  B6,  E6,  C6,  F6,  Hc, Gc, 2)
        ROW(A7,  D7,  B7,  E7,  C7,  F7,  Hc, Gc, 3)
        ROW(A8,  D8,  B8,  E8,  C8,  F8,  He, Ge, 0)
        ROW(A9,  D9,  B9,  E9,  C9,  F9,  He, Ge, 1)
        ROW(A10, D10, B10, E10, C10, F10, He, Ge, 2)
        ROW(A11, D11, B11, E11, C11, F11, He, Ge, 3)
        ROW(A12, D12, B12, E12, C12, F12, Hg, Gg, 0)
        ROW(A13, D13, B13, E13, C13, F13, Hg, Gg, 1)
        ROW(A14, D14, B14, E14, C14, F14, Hg, Gg, 2)
        ROW(A15, D15, B15, E15, C15, F15, Hg, Gg, 3)

        float acc0a = s0a;
        float acc0b = s0b;
        float acc1a = s1a + s2a;
        float acc1b = s1b + s2b;

        // s-butterfly (DPP xor1): both s-lanes hold full row sums.
        acc0a += dpp_mov<DPP_XOR1>(acc0a);
        acc0b += dpp_mov<DPP_XOR1>(acc0b);
        acc1a += dpp_mov<DPP_XOR1>(acc1a);
        acc1b += dpp_mov<DPP_XOR1>(acc1b);

        // Per-lane layer: s=0 -> L0(t), s=1 -> L1(t-1). One activation per n.
        float za  = ss ? acc1a : acc0a;
        float zb  = ss ? acc1b : acc0b;
        float eza = fexp2(kk2 * za);
        float ezb = fexp2(kk2 * zb);
        float va  = fmaf(mm, __builtin_amdgcn_rcpf(1.f + eza), aa);
        float vb  = fmaf(mm, __builtin_amdgcn_rcpf(1.f + ezb), aa);

        // Gate combine, all DPP (independent per n-path):
        //  p=0 quad (i,i,g,g): ig = val * xor2(val)     [per s]
        //  row_shr:4 hands ig to the p=1 quad (f,f,o,o) [dest i <- src i-4]
        //  f/o broadcast per s via quad_perm 0x44/0xEE
        float igqa = va * dpp_mov<DPP_XOR2>(va);
        float igqb = vb * dpp_mov<DPP_XOR2>(vb);
        float iga  = dpp_mov<DPP_SHR4>(igqa);
        float igb  = dpp_mov<DPP_SHR4>(igqb);
        float fba  = dpp_mov<DPP_FB>(va);
        float fbb  = dpp_mov<DPP_FB>(vb);
        float oba  = dpp_mov<DPP_OB>(va);
        float obb  = dpp_mov<DPP_OB>(vb);

        float cna = fmaf(fba, cca, iga);
        float cnb = fmaf(fbb, ccb, igb);
        float hna = oba * ftanh2(cna);
        float hnb = obb * ftanh2(cnb);
        bool ok = ss ? (t > 0) : (t < TT);       // L1 skip at 0, L0 at TT
        cca = ok ? cna : cca;
        ccb = ok ? cnb : ccb;
        if (wlane && ok) {
            // Adjacent na,nb -> single packed h2 (b32) store.
            *(h2*)&hbuf[(t + 1) & 1][hoff] = h2{(_Float16)hna, (_Float16)hnb};
        }

        __syncthreads();                         // h exchange (double-buffered)
    }
    #undef ROW

    // FC on final h1 = h1(TT-1), in hbuf[(TT+1)&1][64..128).
    if (tid < EE) {
        const _Float16* h1f = &hbuf[(TT + 1) & 1][HH];
        float acc = b_fc[tid];
        const float4* wf = (const float4*)(W_fc + tid * HH);
        #pragma unroll
        for (int k = 0; k < HH / 4; ++k) {
            float4 v = wf[k];
            acc = fmaf(v.x, (float)h1f[4*k+0], acc);
            acc = fmaf(v.y, (float)h1f[4*k+1], acc);
            acc = fmaf(v.z, (float)h1f[4*k+2], acc);
            acc = fmaf(v.w, (float)h1f[4*k+3], acc);
        }
        out[(size_t)b * EE + tid] = acc;
    }
}

extern "C" void kernel_launch(void* const* d_in, const int* in_sizes, int n_in,
                              void* d_out, int out_size, void* d_ws, size_t ws_size,
                              hipStream_t stream) {
    const float* x     = (const float*)d_in[0];
    const float* W_ih0 = (const float*)d_in[1];
    const float* W_hh0 = (const float*)d_in[2];
    const float* b_ih0 = (const float*)d_in[3];
    const float* b_hh0 = (const float*)d_in[4];
    const float* W_ih1 = (const float*)d_in[5];
    const float* W_hh1 = (const float*)d_in[6];
    const float* b_ih1 = (const float*)d_in[7];
    const float* b_hh1 = (const float*)d_in[8];
    const float* W_fc  = (const float*)d_in[9];
    const float* b_fc  = (const float*)d_in[10];
    float* out = (float*)d_out;

    lstm2_fc_kernel<<<dim3(NB), dim3(256), 0, stream>>>(
        x, W_ih0, W_hh0, b_ih0, b_hh0, W_ih1, W_hh1, b_ih1, b_hh1, W_fc, b_fc, out);
}